// Round 1
// baseline (5708.932 us; speedup 1.0000x reference)
//
#include <hip/hip_runtime.h>
#include <hip/hip_bf16.h>

typedef __attribute__((ext_vector_type(8))) short bf16x8;   // 8 bf16 = 4 VGPRs (MFMA A/B frag)
typedef __attribute__((ext_vector_type(4))) short short4v;  // 4 bf16 store
typedef __attribute__((ext_vector_type(4))) float f32x4;    // MFMA C/D frag

#define N_IN  60000
#define N_OUT 160000
#define C     128
#define EPS   1e-3f
#define SLOPE 0.01f

__device__ inline short f2bf(float f) {            // RNE f32 -> bf16
    unsigned u = __builtin_bit_cast(unsigned, f);
    u += 0x7FFFu + ((u >> 16) & 1u);
    return (short)(u >> 16);
}
__device__ inline float lrelu(float x) { return x > 0.f ? x : SLOPE * x; }

// ---------------- elementwise helpers ----------------
__global__ __launch_bounds__(256) void k_convert(const float* __restrict__ in,
                                                 short* __restrict__ out, int count4) {
    int i = blockIdx.x * 256 + threadIdx.x, stride = gridDim.x * 256;
    for (; i < count4; i += stride) {
        f32x4 v = ((const f32x4*)in)[i];
        short4v o;
        o.x = f2bf(v.x); o.y = f2bf(v.y); o.z = f2bf(v.z); o.w = f2bf(v.w);
        ((short4v*)out)[i] = o;
    }
}

__global__ __launch_bounds__(256) void k_copy(const float* __restrict__ in,
                                              float* __restrict__ out, int count4) {
    int i = blockIdx.x * 256 + threadIdx.x, stride = gridDim.x * 256;
    for (; i < count4; i += stride) ((f32x4*)out)[i] = ((const f32x4*)in)[i];
}

// ---------------- sparse conv: gather -> MFMA -> atomic scatter ----------------
// feat: bf16 [n_in][128]; W: f32 [taps][128][128]; out: f32 [n_out][128] (pre-initialized)
// grid = (blocks_per_tap, taps); block = 256 (4 waves), each block-iter does 64 p-rows.
__global__ __launch_bounds__(256) void k_conv(const short* __restrict__ feat,
                                              const float* __restrict__ W,
                                              const int* __restrict__ idx_in,
                                              const int* __restrict__ idx_out,
                                              float* __restrict__ out,
                                              int P, int ntiles) {
    const int k    = blockIdx.y;
    const int lane = threadIdx.x & 63;
    const int wave = threadIdx.x >> 6;
    const int l15  = lane & 15, lhi = lane >> 4;
    const int wcol0 = wave * 32;                       // this wave's 32-col slice of C

    const float* Wk  = W + (size_t)k * C * C;
    const int* iin   = idx_in  + (size_t)k * P;
    const int* iout  = idx_out + (size_t)k * P;

    // Hoist B fragments (W[k], K=c_in x N=c_out) into registers for the whole kernel.
    // B layout: elem j of lane = B[k0+j][col], k0 = kk*32 + (lane>>4)*8, col = wcol0+16n+(lane&15)
    bf16x8 bfr[2][4];
#pragma unroll
    for (int n = 0; n < 2; n++)
#pragma unroll
        for (int kk = 0; kk < 4; kk++) {
            const int co = wcol0 + 16 * n + l15;
            const int k0 = kk * 32 + lhi * 8;
            bf16x8 b;
#pragma unroll
            for (int j = 0; j < 8; j++) b[j] = f2bf(Wk[(size_t)(k0 + j) * C + co]);
            bfr[n][kk] = b;
        }

    const f32x4 zero4 = {0.f, 0.f, 0.f, 0.f};
    for (int t = blockIdx.x; t < ntiles; t += gridDim.x) {
        const int p0 = t * 64;
        f32x4 acc[4][2];
#pragma unroll
        for (int m = 0; m < 4; m++) { acc[m][0] = zero4; acc[m][1] = zero4; }

#pragma unroll
        for (int m = 0; m < 4; m++) {
            // A frag: row = lane&15 (p-row within 16-block), k = kk*32+(lane>>4)*8+j (c_in)
            const int pa = p0 + 16 * m + l15;
            bf16x8 afr[4];
            if (pa < P) {
                const int row = iin[pa];
                const bf16x8* rp = (const bf16x8*)(feat + (size_t)row * C);
#pragma unroll
                for (int kk = 0; kk < 4; kk++) afr[kk] = rp[kk * 4 + lhi];
            } else {
#pragma unroll
                for (int kk = 0; kk < 4; kk++) {
                    bf16x8 z;
#pragma unroll
                    for (int j = 0; j < 8; j++) z[j] = 0;
                    afr[kk] = z;
                }
            }
#pragma unroll
            for (int kk = 0; kk < 4; kk++) {
                acc[m][0] = __builtin_amdgcn_mfma_f32_16x16x32_bf16(afr[kk], bfr[0][kk], acc[m][0], 0, 0, 0);
                acc[m][1] = __builtin_amdgcn_mfma_f32_16x16x32_bf16(afr[kk], bfr[1][kk], acc[m][1], 0, 0, 0);
            }
        }

        // scatter: D row = (lane>>4)*4 + reg, col = lane&15
#pragma unroll
        for (int m = 0; m < 4; m++) {
#pragma unroll
            for (int r = 0; r < 4; r++) {
                const int pr = p0 + 16 * m + lhi * 4 + r;
                if (pr < P) {
                    const int orow = iout[pr];
                    float* op = out + (size_t)orow * C + wcol0 + l15;
                    unsafeAtomicAdd(op, acc[m][0][r]);
                    unsafeAtomicAdd(op + 16, acc[m][1][r]);
                }
            }
        }
    }
}

// ---------------- BN stats: per-channel sum / sumsq of lrelu(x) ----------------
__global__ __launch_bounds__(256) void k_stats(const float* __restrict__ x, int n,
                                               float* __restrict__ stats) {
    const int t  = threadIdx.x;
    const int c4 = (t & 31) * 4;
    const int rg = t >> 5;                              // 0..7
    float s0 = 0, s1 = 0, s2 = 0, s3 = 0, q0 = 0, q1 = 0, q2 = 0, q3 = 0;
    for (int r = blockIdx.x * 8 + rg; r < n; r += gridDim.x * 8) {
        f32x4 v = *(const f32x4*)(x + (size_t)r * C + c4);
        float y0 = lrelu(v.x), y1 = lrelu(v.y), y2 = lrelu(v.z), y3 = lrelu(v.w);
        s0 += y0; s1 += y1; s2 += y2; s3 += y3;
        q0 += y0 * y0; q1 += y1 * y1; q2 += y2 * y2; q3 += y3 * y3;
    }
    __shared__ float rs[8][128];
    __shared__ float rq[8][128];
    rs[rg][c4] = s0; rs[rg][c4 + 1] = s1; rs[rg][c4 + 2] = s2; rs[rg][c4 + 3] = s3;
    rq[rg][c4] = q0; rq[rg][c4 + 1] = q1; rq[rg][c4 + 2] = q2; rq[rg][c4 + 3] = q3;
    __syncthreads();
    if (t < 128) {
        float S = 0, Q = 0;
#pragma unroll
        for (int g = 0; g < 8; g++) { S += rs[g][t]; Q += rq[g][t]; }
        unsafeAtomicAdd(&stats[t], S);
        unsafeAtomicAdd(&stats[128 + t], Q);
    }
}

// ---------------- apply LReLU + BN; emit bf16 table and/or f32 ----------------
__global__ __launch_bounds__(256) void k_apply(const float* x, const float* __restrict__ stats,
                                               const float* __restrict__ g, const float* __restrict__ b,
                                               int n, float inv_n,
                                               short* __restrict__ out_bf, float* out_f) {
    __shared__ float sc[128], sh[128];
    const int t = threadIdx.x;
    if (t < 128) {
        float m = stats[t] * inv_n;
        float v = stats[128 + t] * inv_n - m * m;
        float s = rsqrtf(v + EPS) * g[t];
        sc[t] = s; sh[t] = b[t] - m * s;
    }
    __syncthreads();
    const int c4 = (t & 31) * 4;
    const int rg = t >> 5;
    const float s0 = sc[c4], s1 = sc[c4 + 1], s2 = sc[c4 + 2], s3 = sc[c4 + 3];
    const float h0 = sh[c4], h1 = sh[c4 + 1], h2 = sh[c4 + 2], h3 = sh[c4 + 3];
    for (int r = blockIdx.x * 8 + rg; r < n; r += gridDim.x * 8) {
        f32x4 v = *(const f32x4*)(x + (size_t)r * C + c4);
        f32x4 o;
        o.x = lrelu(v.x) * s0 + h0;
        o.y = lrelu(v.y) * s1 + h1;
        o.z = lrelu(v.z) * s2 + h2;
        o.w = lrelu(v.w) * s3 + h3;
        if (out_f) *(f32x4*)(out_f + (size_t)r * C + c4) = o;
        if (out_bf) {
            short4v ob;
            ob.x = f2bf(o.x); ob.y = f2bf(o.y); ob.z = f2bf(o.z); ob.w = f2bf(o.w);
            *(short4v*)(out_bf + (size_t)r * C + c4) = ob;
        }
    }
}

extern "C" void kernel_launch(void* const* d_in, const int* in_sizes, int n_in,
                              void* d_out, int out_size, void* d_ws, size_t ws_size,
                              hipStream_t stream) {
    const float* x_feat = (const float*)d_in[0];
    const float* skip   = (const float*)d_in[1];
    const float* W_t  = (const float*)d_in[2];
    const float* g_t  = (const float*)d_in[3];
    const float* b_t  = (const float*)d_in[4];
    const float* W_up = (const float*)d_in[5];
    const float* W1   = (const float*)d_in[6];
    const float* g1   = (const float*)d_in[7];
    const float* b1   = (const float*)d_in[8];
    const float* W2   = (const float*)d_in[9];
    const float* g2   = (const float*)d_in[10];
    const float* b2   = (const float*)d_in[11];
    const float* W3   = (const float*)d_in[12];
    const float* g3   = (const float*)d_in[13];
    const float* b3   = (const float*)d_in[14];
    const int* ti_in  = (const int*)d_in[15];
    const int* ti_out = (const int*)d_in[16];
    const int* ui_in  = (const int*)d_in[17];
    const int* ui_out = (const int*)d_in[18];
    const int* i1_in  = (const int*)d_in[19];
    const int* i1_out = (const int*)d_in[20];
    const int* i2_in  = (const int*)d_in[21];
    const int* i2_out = (const int*)d_in[22];
    const int* i3_in  = (const int*)d_in[23];
    const int* i3_out = (const int*)d_in[24];

    // workspace: two bf16 tables + stats (~82 MB). d_out is the single f32 accumulator table.
    char*  ws    = (char*)d_ws;
    short* BFA   = (short*)ws;                           // 40,960,000 B
    short* BFB   = (short*)(ws + 40960000);              // 40,960,000 B
    float* stats = (float*)(ws + 81920000);              // 1 KB
    short* XBF   = BFB;                                  // x_feat bf16 aliases BFB (disjoint lifetime)
    float* outF  = (float*)d_out;

    // ---- layer t: trans_dilao (27 taps, P=N_IN) -> lrelu -> bn -> BFA ----
    k_convert<<<1024, 256, 0, stream>>>(x_feat, XBF, N_IN * C / 4);
    hipMemsetAsync(outF, 0, (size_t)N_IN * C * 4, stream);
    k_conv<<<dim3(64, 27), 256, 0, stream>>>(XBF, W_t, ti_in, ti_out, outF, N_IN, (N_IN + 63) / 64);
    hipMemsetAsync(stats, 0, 1024, stream);
    k_stats<<<512, 256, 0, stream>>>(outF, N_IN, stats);
    k_apply<<<512, 256, 0, stream>>>(outF, stats, g_t, b_t, N_IN, 1.f / N_IN, BFA, nullptr);

    // ---- upsample conv (27 taps, P=N_OUT) + skip residual -> BFB (bf16 copy of A2) ----
    k_copy<<<1024, 256, 0, stream>>>(skip, outF, N_OUT * C / 4);
    k_conv<<<dim3(64, 27), 256, 0, stream>>>(BFA, W_up, ui_in, ui_out, outF, N_OUT, N_OUT / 64);
    k_convert<<<1024, 256, 0, stream>>>(outF, BFB, N_OUT * C / 4);

    // ---- conv1 (9 taps) -> lrelu -> bn -> BFA ----
    hipMemsetAsync(outF, 0, (size_t)N_OUT * C * 4, stream);
    k_conv<<<dim3(192, 9), 256, 0, stream>>>(BFB, W1, i1_in, i1_out, outF, N_OUT, N_OUT / 64);
    hipMemsetAsync(stats, 0, 1024, stream);
    k_stats<<<512, 256, 0, stream>>>(outF, N_OUT, stats);
    k_apply<<<512, 256, 0, stream>>>(outF, stats, g1, b1, N_OUT, 1.f / N_OUT, BFA, nullptr);

    // ---- conv2 (9 taps) -> lrelu -> bn -> BFB ----
    hipMemsetAsync(outF, 0, (size_t)N_OUT * C * 4, stream);
    k_conv<<<dim3(192, 9), 256, 0, stream>>>(BFA, W2, i2_in, i2_out, outF, N_OUT, N_OUT / 64);
    hipMemsetAsync(stats, 0, 1024, stream);
    k_stats<<<512, 256, 0, stream>>>(outF, N_OUT, stats);
    k_apply<<<512, 256, 0, stream>>>(outF, stats, g2, b2, N_OUT, 1.f / N_OUT, BFB, nullptr);

    // ---- conv3 (27 taps) -> lrelu -> bn -> d_out (f32, in place) ----
    hipMemsetAsync(outF, 0, (size_t)N_OUT * C * 4, stream);
    k_conv<<<dim3(64, 27), 256, 0, stream>>>(BFB, W3, i3_in, i3_out, outF, N_OUT, N_OUT / 64);
    hipMemsetAsync(stats, 0, 1024, stream);
    k_stats<<<512, 256, 0, stream>>>(outF, N_OUT, stats);
    k_apply<<<512, 256, 0, stream>>>(outF, stats, g3, b3, N_OUT, 1.f / N_OUT, nullptr, outF);
}

// Round 3
// 3070.500 us; speedup vs baseline: 1.8593x; 1.8593x over previous
//
#include <hip/hip_runtime.h>
#include <hip/hip_bf16.h>

typedef __attribute__((ext_vector_type(8))) short bf16x8;      // 8 bf16 = 4 VGPRs (MFMA A/B frag)
typedef __attribute__((ext_vector_type(4))) short short4v;     // 4 bf16
typedef __attribute__((ext_vector_type(2))) _Float16 half2v;   // packed fp16 pair
typedef __attribute__((ext_vector_type(4))) _Float16 half4v;   // 4 fp16 (8 B)
typedef __attribute__((ext_vector_type(4))) float f32x4;       // MFMA C/D frag

#define N_IN  60000
#define N_OUT 160000
#define C     128
#define EPS   1e-3f
#define SLOPE 0.01f

__device__ inline short f2bf(float f) {            // RNE f32 -> bf16
    unsigned u = __builtin_bit_cast(unsigned, f);
    u += 0x7FFFu + ((u >> 16) & 1u);
    return (short)(u >> 16);
}
__device__ inline float bf2f(short s) {
    unsigned u = ((unsigned)(unsigned short)s) << 16;
    return __builtin_bit_cast(float, u);
}
__device__ inline float lrelu(float x) { return x > 0.f ? x : SLOPE * x; }

// packed fp16 atomic add (2 fp16 per dword op, HW fadd at L2)
__device__ inline void pk_atomic_add_f16(_Float16* addr, float lo, float hi) {
    half2v v; v.x = (_Float16)lo; v.y = (_Float16)hi;
#if __has_builtin(__builtin_amdgcn_global_atomic_fadd_v2f16)
    __builtin_amdgcn_global_atomic_fadd_v2f16((half2v*)addr, v);
#else
    unsigned pk = __builtin_bit_cast(unsigned, v);
    asm volatile("global_atomic_pk_add_f16 %0, %1, off" :: "v"(addr), "v"(pk) : "memory");
#endif
}

// ---------------- converts ----------------
__global__ __launch_bounds__(256) void k_f32_to_bf16(const float* __restrict__ in,
                                                     short* __restrict__ out, int count4) {
    int i = blockIdx.x * 256 + threadIdx.x, stride = gridDim.x * 256;
    for (; i < count4; i += stride) {
        f32x4 v = ((const f32x4*)in)[i];
        short4v o;
        o.x = f2bf(v.x); o.y = f2bf(v.y); o.z = f2bf(v.z); o.w = f2bf(v.w);
        ((short4v*)out)[i] = o;
    }
}

__global__ __launch_bounds__(256) void k_f32_to_f16(const float* __restrict__ in,
                                                    _Float16* __restrict__ out, int count4) {
    int i = blockIdx.x * 256 + threadIdx.x, stride = gridDim.x * 256;
    for (; i < count4; i += stride) {
        f32x4 v = ((const f32x4*)in)[i];
        half4v o;
        o.x = (_Float16)v.x; o.y = (_Float16)v.y; o.z = (_Float16)v.z; o.w = (_Float16)v.w;
        ((half4v*)out)[i] = o;
    }
}

__global__ __launch_bounds__(256) void k_f16_to_bf16(const _Float16* __restrict__ in,
                                                     short* __restrict__ out, int count4) {
    int i = blockIdx.x * 256 + threadIdx.x, stride = gridDim.x * 256;
    for (; i < count4; i += stride) {
        half4v v = ((const half4v*)in)[i];
        short4v o;
        o.x = f2bf((float)v.x); o.y = f2bf((float)v.y);
        o.z = f2bf((float)v.z); o.w = f2bf((float)v.w);
        ((short4v*)out)[i] = o;
    }
}

// ---------------- sparse conv: gather -> MFMA -> pk-fp16 atomic scatter ----------------
// feat: bf16 [*][128]; W: f32 [taps][128][128]; out: fp16 [n_out][128] accumulator (pre-init)
__global__ __launch_bounds__(256) void k_conv(const short* __restrict__ feat,
                                              const float* __restrict__ W,
                                              const int* __restrict__ idx_in,
                                              const int* __restrict__ idx_out,
                                              _Float16* __restrict__ out,
                                              int P, int ntiles) {
    const int k    = blockIdx.y;
    const int lane = threadIdx.x & 63;
    const int wave = threadIdx.x >> 6;
    const int l15  = lane & 15, lhi = lane >> 4;
    const int wcol0 = wave * 32;

    const float* Wk = W + (size_t)k * C * C;
    const int* iin  = idx_in  + (size_t)k * P;
    const int* iout = idx_out + (size_t)k * P;

    // B fragments (W[k]) hoisted into registers for the whole kernel.
    bf16x8 bfr[2][4];
#pragma unroll
    for (int n = 0; n < 2; n++)
#pragma unroll
        for (int kk = 0; kk < 4; kk++) {
            const int co = wcol0 + 16 * n + l15;
            const int k0 = kk * 32 + lhi * 8;
            bf16x8 b;
#pragma unroll
            for (int j = 0; j < 8; j++) b[j] = f2bf(Wk[(size_t)(k0 + j) * C + co]);
            bfr[n][kk] = b;
        }

    int t = blockIdx.x;
    if (t >= ntiles) return;
    const int stride = gridDim.x;

    // prologue: indices + out-rows + A-frags for tile t; then prefetch next indices
    int ix[4]; int4 io[4];
#pragma unroll
    for (int m = 0; m < 4; m++) {
        int pa = t * 64 + 16 * m + l15;
        ix[m] = (pa < P) ? iin[pa] : -1;
        int pb = t * 64 + 16 * m + lhi * 4;
        io[m] = (pb < P) ? *(const int4*)(iout + pb) : make_int4(0, 0, 0, 0);
    }
    bf16x8 afr[4][4];
#pragma unroll
    for (int m = 0; m < 4; m++) {
        if (ix[m] >= 0) {
            const bf16x8* rp = (const bf16x8*)(feat + (size_t)ix[m] * C);
#pragma unroll
            for (int kk = 0; kk < 4; kk++) afr[m][kk] = rp[kk * 4 + lhi];
        } else {
#pragma unroll
            for (int kk = 0; kk < 4; kk++) {
                bf16x8 z;
#pragma unroll
                for (int j = 0; j < 8; j++) z[j] = 0;
                afr[m][kk] = z;
            }
        }
    }
    {   // ix <- indices for tile t+stride
        int tn = t + stride;
#pragma unroll
        for (int m = 0; m < 4; m++) {
            int pa = tn * 64 + 16 * m + l15;
            ix[m] = (tn < ntiles && pa < P) ? iin[pa] : -1;
        }
    }

    const f32x4 zero4 = {0.f, 0.f, 0.f, 0.f};
    while (t < ntiles) {
        const int tn = t + stride;
        // ---- MFMA on current frags ----
        f32x4 acc[4][2];
#pragma unroll
        for (int m = 0; m < 4; m++) { acc[m][0] = zero4; acc[m][1] = zero4; }
#pragma unroll
        for (int m = 0; m < 4; m++)
#pragma unroll
            for (int kk = 0; kk < 4; kk++) {
                acc[m][0] = __builtin_amdgcn_mfma_f32_16x16x32_bf16(afr[m][kk], bfr[0][kk], acc[m][0], 0, 0, 0);
                acc[m][1] = __builtin_amdgcn_mfma_f32_16x16x32_bf16(afr[m][kk], bfr[1][kk], acc[m][1], 0, 0, 0);
            }

        // ---- prefetch next tile BEFORE issuing atomics (no wait ever drains atomics) ----
        int4 ioN[4];
#pragma unroll
        for (int m = 0; m < 4; m++) {
            int pb = tn * 64 + 16 * m + lhi * 4;
            ioN[m] = (tn < ntiles && pb < P) ? *(const int4*)(iout + pb) : make_int4(0, 0, 0, 0);
        }
#pragma unroll
        for (int m = 0; m < 4; m++) {
            if (ix[m] >= 0) {
                const bf16x8* rp = (const bf16x8*)(feat + (size_t)ix[m] * C);
#pragma unroll
                for (int kk = 0; kk < 4; kk++) afr[m][kk] = rp[kk * 4 + lhi];
            } else {
#pragma unroll
                for (int kk = 0; kk < 4; kk++) {
                    bf16x8 z;
#pragma unroll
                    for (int j = 0; j < 8; j++) z[j] = 0;
                    afr[m][kk] = z;
                }
            }
        }
        {   // ix <- indices for tile t+2*stride
            int t2 = tn + stride;
#pragma unroll
            for (int m = 0; m < 4; m++) {
                int pa = t2 * 64 + 16 * m + l15;
                ix[m] = (t2 < ntiles && pa < P) ? iin[pa] : -1;
            }
        }

        // ---- scatter current tile: pair columns across lanes, pk-fp16 atomics ----
#pragma unroll
        for (int m = 0; m < 4; m++) {
            const int pbase = t * 64 + 16 * m + lhi * 4;
            const int4 ro = io[m];
#pragma unroll
            for (int r = 0; r < 4; r++) {
                float v0 = acc[m][0][r], v1 = acc[m][1][r];
                float x0 = __shfl_xor(v0, 1, 64);
                float x1 = __shfl_xor(v1, 1, 64);
                if (pbase < P) {
                    int col; float lo, hi;
                    if ((l15 & 1) == 0) { lo = v0; hi = x0; col = wcol0 + l15; }
                    else                { lo = x1; hi = v1; col = wcol0 + 15 + l15; }
                    const int orow = (&ro.x)[r];
                    pk_atomic_add_f16(out + (size_t)orow * C + col, lo, hi);
                }
            }
        }
#pragma unroll
        for (int m = 0; m < 4; m++) io[m] = ioN[m];
        t = tn;
    }
}

// ---------------- BN stats over fp16 table: per-channel sum / sumsq of lrelu ----------------
__global__ __launch_bounds__(256) void k_stats(const _Float16* __restrict__ x, int n,
                                               float* __restrict__ stats) {
    const int t  = threadIdx.x;
    const int c4 = (t & 31) * 4;
    const int rg = t >> 5;
    float s0 = 0, s1 = 0, s2 = 0, s3 = 0, q0 = 0, q1 = 0, q2 = 0, q3 = 0;
    for (int r = blockIdx.x * 8 + rg; r < n; r += gridDim.x * 8) {
        half4v v = *(const half4v*)(x + (size_t)r * C + c4);
        float y0 = lrelu((float)v.x), y1 = lrelu((float)v.y);
        float y2 = lrelu((float)v.z), y3 = lrelu((float)v.w);
        s0 += y0; s1 += y1; s2 += y2; s3 += y3;
        q0 += y0 * y0; q1 += y1 * y1; q2 += y2 * y2; q3 += y3 * y3;
    }
    __shared__ float rs[8][128];
    __shared__ float rq[8][128];
    rs[rg][c4] = s0; rs[rg][c4 + 1] = s1; rs[rg][c4 + 2] = s2; rs[rg][c4 + 3] = s3;
    rq[rg][c4] = q0; rq[rg][c4 + 1] = q1; rq[rg][c4 + 2] = q2; rq[rg][c4 + 3] = q3;
    __syncthreads();
    if (t < 128) {
        float S = 0, Q = 0;
#pragma unroll
        for (int g = 0; g < 8; g++) { S += rs[g][t]; Q += rq[g][t]; }
        unsafeAtomicAdd(&stats[t], S);
        unsafeAtomicAdd(&stats[128 + t], Q);
    }
}

// ---------------- apply LReLU + BN on fp16 table; emit bf16 table and/or f32 ----------------
__global__ __launch_bounds__(256) void k_apply(const _Float16* x, const float* __restrict__ stats,
                                               const float* __restrict__ g, const float* __restrict__ b,
                                               int n, float inv_n,
                                               short* __restrict__ out_bf, float* out_f) {
    __shared__ float sc[128], sh[128];
    const int t = threadIdx.x;
    if (t < 128) {
        float m = stats[t] * inv_n;
        float v = stats[128 + t] * inv_n - m * m;
        float s = rsqrtf(v + EPS) * g[t];
        sc[t] = s; sh[t] = b[t] - m * s;
    }
    __syncthreads();
    const int c4 = (t & 31) * 4;
    const int rg = t >> 5;
    const float s0 = sc[c4], s1 = sc[c4 + 1], s2 = sc[c4 + 2], s3 = sc[c4 + 3];
    const float h0 = sh[c4], h1 = sh[c4 + 1], h2 = sh[c4 + 2], h3 = sh[c4 + 3];
    for (int r = blockIdx.x * 8 + rg; r < n; r += gridDim.x * 8) {
        half4v v = *(const half4v*)(x + (size_t)r * C + c4);
        f32x4 o;
        o.x = lrelu((float)v.x) * s0 + h0;
        o.y = lrelu((float)v.y) * s1 + h1;
        o.z = lrelu((float)v.z) * s2 + h2;
        o.w = lrelu((float)v.w) * s3 + h3;
        if (out_f) *(f32x4*)(out_f + (size_t)r * C + c4) = o;
        if (out_bf) {
            short4v ob;
            ob.x = f2bf(o.x); ob.y = f2bf(o.y); ob.z = f2bf(o.z); ob.w = f2bf(o.w);
            *(short4v*)(out_bf + (size_t)r * C + c4) = ob;
        }
    }
}

extern "C" void kernel_launch(void* const* d_in, const int* in_sizes, int n_in,
                              void* d_out, int out_size, void* d_ws, size_t ws_size,
                              hipStream_t stream) {
    const float* x_feat = (const float*)d_in[0];
    const float* skip   = (const float*)d_in[1];
    const float* W_t  = (const float*)d_in[2];
    const float* g_t  = (const float*)d_in[3];
    const float* b_t  = (const float*)d_in[4];
    const float* W_up = (const float*)d_in[5];
    const float* W1   = (const float*)d_in[6];
    const float* g1   = (const float*)d_in[7];
    const float* b1   = (const float*)d_in[8];
    const float* W2   = (const float*)d_in[9];
    const float* g2   = (const float*)d_in[10];
    const float* b2   = (const float*)d_in[11];
    const float* W3   = (const float*)d_in[12];
    const float* g3   = (const float*)d_in[13];
    const float* b3   = (const float*)d_in[14];
    const int* ti_in  = (const int*)d_in[15];
    const int* ti_out = (const int*)d_in[16];
    const int* ui_in  = (const int*)d_in[17];
    const int* ui_out = (const int*)d_in[18];
    const int* i1_in  = (const int*)d_in[19];
    const int* i1_out = (const int*)d_in[20];
    const int* i2_in  = (const int*)d_in[21];
    const int* i2_out = (const int*)d_in[22];
    const int* i3_in  = (const int*)d_in[23];
    const int* i3_out = (const int*)d_in[24];

    // ws: two 41MB buffers (bf16 feat tables / fp16 accumulator) + stats.
    // d_out lower half doubles as the fp16 accumulator H for convs t/up/1/2.
    char*     ws    = (char*)d_ws;
    short*    A     = (short*)ws;                        // 40,960,000 B (bf16 table)
    short*    B     = (short*)(ws + 40960000);           // 40,960,000 B (bf16 table)
    _Float16* Bh    = (_Float16*)B;                      // same bytes viewed as fp16 accum
    float*    stats = (float*)(ws + 81920000);           // 1 KB
    _Float16* H     = (_Float16*)d_out;                  // 41 MB fp16 accumulator
    float*    outF  = (float*)d_out;

    // ---- trans_dilao (27 taps, P=N_IN): A(bf16 x) -> H -> lrelu+bn -> B ----
    k_f32_to_bf16<<<1024, 256, 0, stream>>>(x_feat, A, N_IN * C / 4);
    hipMemsetAsync(H, 0, (size_t)N_IN * C * 2, stream);
    k_conv<<<dim3(80, 27), 256, 0, stream>>>(A, W_t, ti_in, ti_out, H, N_IN, (N_IN + 63) / 64);
    hipMemsetAsync(stats, 0, 1024, stream);
    k_stats<<<512, 256, 0, stream>>>(H, N_IN, stats);
    k_apply<<<512, 256, 0, stream>>>(H, stats, g_t, b_t, N_IN, 1.f / N_IN, B, nullptr);

    // ---- upsample (27 taps): H = fp16(skip); B -> H; then H -> A (bf16 feat for conv1) ----
    k_f32_to_f16<<<2048, 256, 0, stream>>>(skip, H, N_OUT * C / 4);
    k_conv<<<dim3(80, 27), 256, 0, stream>>>(B, W_up, ui_in, ui_out, H, N_OUT, N_OUT / 64);
    k_f16_to_bf16<<<2048, 256, 0, stream>>>(H, A, N_OUT * C / 4);

    // ---- conv1 (9 taps): A -> H -> lrelu+bn -> B ----
    hipMemsetAsync(H, 0, (size_t)N_OUT * C * 2, stream);
    k_conv<<<dim3(240, 9), 256, 0, stream>>>(A, W1, i1_in, i1_out, H, N_OUT, N_OUT / 64);
    hipMemsetAsync(stats, 0, 1024, stream);
    k_stats<<<512, 256, 0, stream>>>(H, N_OUT, stats);
    k_apply<<<512, 256, 0, stream>>>(H, stats, g1, b1, N_OUT, 1.f / N_OUT, B, nullptr);

    // ---- conv2 (9 taps): B -> H -> lrelu+bn -> A ----
    hipMemsetAsync(H, 0, (size_t)N_OUT * C * 2, stream);
    k_conv<<<dim3(240, 9), 256, 0, stream>>>(B, W2, i2_in, i2_out, H, N_OUT, N_OUT / 64);
    hipMemsetAsync(stats, 0, 1024, stream);
    k_stats<<<512, 256, 0, stream>>>(H, N_OUT, stats);
    k_apply<<<512, 256, 0, stream>>>(H, stats, g2, b2, N_OUT, 1.f / N_OUT, A, nullptr);

    // ---- conv3 (27 taps): A -> Bh (ws accum, avoids aliasing final f32 out) -> d_out ----
    hipMemsetAsync(Bh, 0, (size_t)N_OUT * C * 2, stream);
    k_conv<<<dim3(80, 27), 256, 0, stream>>>(A, W3, i3_in, i3_out, Bh, N_OUT, N_OUT / 64);
    hipMemsetAsync(stats, 0, 1024, stream);
    k_stats<<<512, 256, 0, stream>>>(Bh, N_OUT, stats);
    k_apply<<<512, 256, 0, stream>>>(Bh, stats, g3, b3, N_OUT, 1.f / N_OUT, nullptr, outF);
}